// Round 1
// baseline (1247.045 us; speedup 1.0000x reference)
//
#include <hip/hip_runtime.h>

// Head attention: B=32, S=2048, E=64, H=64, fp32, NO causal mask.
// Round 0 baseline: fp32 vector-ALU flash attention.
//   kernel 1: QKV projection (x[B*S,64] @ W[64,64]^T x3) -> d_ws (needs 50.3 MB)
//   kernel 2: flash attention, 64-query tile per block, 64-key tiles via LDS.
// LDS layout: PAD=68 float row stride (16B aligned, breaks power-of-2 bank
// stride); score-phase cols mapped tx+16j and PV-phase dims 4tx+j so every
// LDS access is <=2-way bank aliased (free on gfx950 per m136).

#define BATCH 32
#define SEQ   2048
#define EMB   64
#define HS    64
#define PAD   68

__global__ __launch_bounds__(256) void proj_kernel(
    const float* __restrict__ x,
    const float* __restrict__ Wq,
    const float* __restrict__ Wk,
    const float* __restrict__ Wv,
    float* __restrict__ Q, float* __restrict__ K, float* __restrict__ V)
{
    __shared__ float xs[64][PAD];
    __shared__ float wsh[64][PAD];

    const int t  = threadIdx.x;
    const int tx = t & 15, ty = t >> 4;
    const long row0 = (long)blockIdx.x * 64;

    // stage x tile (64 rows x 64 floats)
#pragma unroll
    for (int i = 0; i < 4; ++i) {
        int idx = t + i * 256;
        int r = idx >> 4, c4 = idx & 15;
        *(float4*)&xs[r][c4 * 4] = ((const float4*)(x + (row0 + r) * EMB))[c4];
    }

#pragma unroll
    for (int m = 0; m < 3; ++m) {
        const float* W = (m == 0) ? Wq : ((m == 1) ? Wk : Wv);
        float* dst     = (m == 0) ? Q  : ((m == 1) ? K  : V);

        __syncthreads();  // wsh free from previous pass readers (also fences xs stage)
#pragma unroll
        for (int i = 0; i < 4; ++i) {
            int idx = t + i * 256;
            int r = idx >> 4, c4 = idx & 15;
            *(float4*)&wsh[r][c4 * 4] = ((const float4*)(W + r * EMB))[c4];
        }
        __syncthreads();

        float acc[4][4];
#pragma unroll
        for (int i = 0; i < 4; ++i)
#pragma unroll
            for (int j = 0; j < 4; ++j) acc[i][j] = 0.f;

#pragma unroll
        for (int e4 = 0; e4 < 16; ++e4) {
            float4 xv[4], wv[4];
#pragma unroll
            for (int i = 0; i < 4; ++i) xv[i] = *(const float4*)&xs[4 * ty + i][e4 * 4];
#pragma unroll
            for (int j = 0; j < 4; ++j) wv[j] = *(const float4*)&wsh[tx + 16 * j][e4 * 4];
#pragma unroll
            for (int i = 0; i < 4; ++i)
#pragma unroll
                for (int j = 0; j < 4; ++j)
                    acc[i][j] += xv[i].x * wv[j].x + xv[i].y * wv[j].y +
                                 xv[i].z * wv[j].z + xv[i].w * wv[j].w;
        }

#pragma unroll
        for (int i = 0; i < 4; ++i)
#pragma unroll
            for (int j = 0; j < 4; ++j)
                dst[(row0 + 4 * ty + i) * HS + tx + 16 * j] = acc[i][j];
    }
}

__global__ __launch_bounds__(256) void attn_kernel(
    const float* __restrict__ Q, const float* __restrict__ K,
    const float* __restrict__ V, float* __restrict__ out)
{
    __shared__ float qs[64][PAD];
    __shared__ float kp[64][PAD];   // K tile; after a barrier, reused for P tile
    __shared__ float vs[64][PAD];

    const int t  = threadIdx.x;
    const int tx = t & 15, ty = t >> 4;
    const int b  = blockIdx.x >> 5;     // 32 q-tiles per batch
    const int qb = blockIdx.x & 31;

    const float* Qb = Q + ((long)b * SEQ + qb * 64) * HS;
    const float* Kb = K + (long)b * SEQ * HS;
    const float* Vb = V + (long)b * SEQ * HS;

    // stage Q tile
#pragma unroll
    for (int i = 0; i < 4; ++i) {
        int idx = t + i * 256;
        int r = idx >> 4, c4 = idx & 15;
        *(float4*)&qs[r][c4 * 4] = ((const float4*)(Qb + r * HS))[c4];
    }

    float m_i[4], l_i[4], o_acc[4][4];
#pragma unroll
    for (int i = 0; i < 4; ++i) {
        m_i[i] = -1e30f;
        l_i[i] = 0.f;
#pragma unroll
        for (int j = 0; j < 4; ++j) o_acc[i][j] = 0.f;
    }

    for (int kt = 0; kt < SEQ / 64; ++kt) {
        __syncthreads();  // previous iter done reading kp/vs (iter 0: fences qs stage)
        const float* Ksrc = Kb + kt * 64 * HS;
        const float* Vsrc = Vb + kt * 64 * HS;
#pragma unroll
        for (int i = 0; i < 4; ++i) {
            int idx = t + i * 256;
            int r = idx >> 4, c4 = idx & 15;
            *(float4*)&kp[r][c4 * 4] = ((const float4*)(Ksrc + r * HS))[c4];
            *(float4*)&vs[r][c4 * 4] = ((const float4*)(Vsrc + r * HS))[c4];
        }
        __syncthreads();

        // scores: row 4ty+i, col tx+16j  (col mapping keeps LDS reads 2-way)
        float s[4][4];
#pragma unroll
        for (int i = 0; i < 4; ++i)
#pragma unroll
            for (int j = 0; j < 4; ++j) s[i][j] = 0.f;

#pragma unroll
        for (int e4 = 0; e4 < 16; ++e4) {
            float4 qv[4], kv[4];
#pragma unroll
            for (int i = 0; i < 4; ++i) qv[i] = *(const float4*)&qs[4 * ty + i][e4 * 4];
#pragma unroll
            for (int j = 0; j < 4; ++j) kv[j] = *(const float4*)&kp[tx + 16 * j][e4 * 4];
#pragma unroll
            for (int i = 0; i < 4; ++i)
#pragma unroll
                for (int j = 0; j < 4; ++j)
                    s[i][j] += qv[i].x * kv[j].x + qv[i].y * kv[j].y +
                               qv[i].z * kv[j].z + qv[i].w * kv[j].w;
        }

        float alpha[4];
#pragma unroll
        for (int i = 0; i < 4; ++i) {
#pragma unroll
            for (int j = 0; j < 4; ++j) s[i][j] *= 0.125f;  // 1/sqrt(64)
            float mx = fmaxf(fmaxf(s[i][0], s[i][1]), fmaxf(s[i][2], s[i][3]));
            mx = fmaxf(mx, __shfl_xor(mx, 1));
            mx = fmaxf(mx, __shfl_xor(mx, 2));
            mx = fmaxf(mx, __shfl_xor(mx, 4));
            mx = fmaxf(mx, __shfl_xor(mx, 8));
            float m_new = fmaxf(m_i[i], mx);
            alpha[i] = __expf(m_i[i] - m_new);
            m_i[i] = m_new;
            float sum = 0.f;
#pragma unroll
            for (int j = 0; j < 4; ++j) {
                s[i][j] = __expf(s[i][j] - m_new);
                sum += s[i][j];
            }
            sum += __shfl_xor(sum, 1);
            sum += __shfl_xor(sum, 2);
            sum += __shfl_xor(sum, 4);
            sum += __shfl_xor(sum, 8);
            l_i[i] = l_i[i] * alpha[i] + sum;
        }

        __syncthreads();  // everyone done reading K tile; reuse kp for P
#pragma unroll
        for (int i = 0; i < 4; ++i)
#pragma unroll
            for (int j = 0; j < 4; ++j)
                kp[4 * ty + i][tx + 16 * j] = s[i][j];
        __syncthreads();

        // O update: dims 4tx+j (contiguous for float4 out-store)
#pragma unroll
        for (int i = 0; i < 4; ++i)
#pragma unroll
            for (int j = 0; j < 4; ++j) o_acc[i][j] *= alpha[i];

#pragma unroll
        for (int k4 = 0; k4 < 16; ++k4) {
            float4 pv[4], vv[4];
#pragma unroll
            for (int i = 0; i < 4; ++i)  pv[i] = *(const float4*)&kp[4 * ty + i][k4 * 4];
#pragma unroll
            for (int kk = 0; kk < 4; ++kk) vv[kk] = *(const float4*)&vs[4 * k4 + kk][4 * tx];
#pragma unroll
            for (int i = 0; i < 4; ++i) {
                o_acc[i][0] += pv[i].x * vv[0].x + pv[i].y * vv[1].x + pv[i].z * vv[2].x + pv[i].w * vv[3].x;
                o_acc[i][1] += pv[i].x * vv[0].y + pv[i].y * vv[1].y + pv[i].z * vv[2].y + pv[i].w * vv[3].y;
                o_acc[i][2] += pv[i].x * vv[0].z + pv[i].y * vv[1].z + pv[i].z * vv[2].z + pv[i].w * vv[3].z;
                o_acc[i][3] += pv[i].x * vv[0].w + pv[i].y * vv[1].w + pv[i].z * vv[2].w + pv[i].w * vv[3].w;
            }
        }
    }

#pragma unroll
    for (int i = 0; i < 4; ++i) {
        float inv = 1.0f / l_i[i];
        float4 r4 = make_float4(o_acc[i][0] * inv, o_acc[i][1] * inv,
                                o_acc[i][2] * inv, o_acc[i][3] * inv);
        ((float4*)(out + ((long)b * SEQ + qb * 64 + 4 * ty + i) * HS))[tx] = r4;
    }
}

extern "C" void kernel_launch(void* const* d_in, const int* in_sizes, int n_in,
                              void* d_out, int out_size, void* d_ws, size_t ws_size,
                              hipStream_t stream)
{
    const float* x  = (const float*)d_in[0];
    const float* Wq = (const float*)d_in[1];
    const float* Wk = (const float*)d_in[2];
    const float* Wv = (const float*)d_in[3];
    float* out = (float*)d_out;

    // workspace: Q,K,V each B*S*H fp32 = 16.8 MB -> 50.3 MB total
    float* Qw = (float*)d_ws;
    float* Kw = Qw + (size_t)BATCH * SEQ * HS;
    float* Vw = Kw + (size_t)BATCH * SEQ * HS;

    proj_kernel<<<(BATCH * SEQ) / 64, 256, 0, stream>>>(x, Wq, Wk, Wv, Qw, Kw, Vw);
    attn_kernel<<<BATCH * (SEQ / 64), 256, 0, stream>>>(Qw, Kw, Vw, out);
}

// Round 2
// 357.358 us; speedup vs baseline: 3.4896x; 3.4896x over previous
//
#include <hip/hip_runtime.h>

// Head attention: B=32, S=2048, E=64, H=64, fp32 in/out, NO causal mask.
// R1: f16 MFMA flash attention.
//  proj_kernel: x @ W^T (x3) in fp32, emit fp16: Qh (pre-scaled by
//    0.125*log2(e) so QK^T lands directly in base-2 softmax domain),
//    Kh row-major [b][s][h], Vt transposed [b][h][s].
//  attn_kernel: 1 block = (batch, 64-q-tile); 4 waves x 16 q-rows each.
//    Per 64-key tile: 8x mfma_f32_16x16x32_f16 (QK), online softmax (exp2,
//    shfl_xor reductions), P C-layout -> A-layout via per-wave LDS scratch,
//    8x MFMA (PV) into fp32 acc. K/V B-fragments load 16B/lane straight from
//    global (L1/L2-served; no staging barriers).

#define BATCH 32
#define SEQ   2048
#define EMB   64
#define HS    64
#define PADF  68
#define QSCALE 0.18033688011112042f   // 0.125 * log2(e)

typedef _Float16 f16x8 __attribute__((ext_vector_type(8)));
typedef float    f32x4 __attribute__((ext_vector_type(4)));

__global__ __launch_bounds__(256) void proj_kernel(
    const float* __restrict__ x,
    const float* __restrict__ Wq,
    const float* __restrict__ Wk,
    const float* __restrict__ Wv,
    _Float16* __restrict__ Qh, _Float16* __restrict__ Kh,
    _Float16* __restrict__ Vt)
{
    __shared__ float xs[64][PADF];
    __shared__ float wsh[64][PADF];

    const int t  = threadIdx.x;
    const int tx = t & 15, ty = t >> 4;
    const long row0 = (long)blockIdx.x * 64;
    const int  b  = (int)(row0 / SEQ);
    const int  s0 = (int)(row0 % SEQ);

#pragma unroll
    for (int i = 0; i < 4; ++i) {
        int idx = t + i * 256;
        int r = idx >> 4, c4 = idx & 15;
        *(float4*)&xs[r][c4 * 4] = ((const float4*)(x + (row0 + r) * EMB))[c4];
    }

#pragma unroll
    for (int m = 0; m < 3; ++m) {
        const float* W = (m == 0) ? Wq : ((m == 1) ? Wk : Wv);

        __syncthreads();
#pragma unroll
        for (int i = 0; i < 4; ++i) {
            int idx = t + i * 256;
            int r = idx >> 4, c4 = idx & 15;
            *(float4*)&wsh[r][c4 * 4] = ((const float4*)(W + r * EMB))[c4];
        }
        __syncthreads();

        float acc[4][4];
#pragma unroll
        for (int i = 0; i < 4; ++i)
#pragma unroll
            for (int j = 0; j < 4; ++j) acc[i][j] = 0.f;

#pragma unroll
        for (int e4 = 0; e4 < 16; ++e4) {
            float4 xv[4], wv[4];
#pragma unroll
            for (int i = 0; i < 4; ++i) xv[i] = *(const float4*)&xs[4 * ty + i][e4 * 4];
#pragma unroll
            for (int j = 0; j < 4; ++j) wv[j] = *(const float4*)&wsh[tx + 16 * j][e4 * 4];
#pragma unroll
            for (int i = 0; i < 4; ++i)
#pragma unroll
                for (int j = 0; j < 4; ++j)
                    acc[i][j] += xv[i].x * wv[j].x + xv[i].y * wv[j].y +
                                 xv[i].z * wv[j].z + xv[i].w * wv[j].w;
        }

        if (m < 2) {
            _Float16* dst = (m == 0) ? Qh : Kh;
            const float cvt = (m == 0) ? QSCALE : 1.0f;
#pragma unroll
            for (int i = 0; i < 4; ++i)
#pragma unroll
                for (int j = 0; j < 4; ++j)
                    dst[(row0 + 4 * ty + i) * HS + tx + 16 * j] =
                        (_Float16)(acc[i][j] * cvt);
        } else {
            // transpose V tile through LDS, emit Vt[b][h][s] fp16 coalesced
            __syncthreads();   // wsh readers done
#pragma unroll
            for (int i = 0; i < 4; ++i)
#pragma unroll
                for (int j = 0; j < 4; ++j)
                    wsh[tx + 16 * j][4 * ty + i] = acc[i][j];
            __syncthreads();

            const int h = t >> 2, seg = t & 3;
            f16x8 v0, v1;
#pragma unroll
            for (int u = 0; u < 8; ++u) {
                v0[u] = (_Float16)wsh[h][seg * 16 + u];
                v1[u] = (_Float16)wsh[h][seg * 16 + 8 + u];
            }
            _Float16* vd = Vt + ((long)b * HS + h) * SEQ + s0 + seg * 16;
            *(f16x8*)(vd)     = v0;
            *(f16x8*)(vd + 8) = v1;
        }
    }
}

__global__ __launch_bounds__(256, 4) void attn_kernel(
    const _Float16* __restrict__ Q, const _Float16* __restrict__ K,
    const _Float16* __restrict__ Vt, float* __restrict__ out)
{
    // per-wave P scratch: 16 rows x 72 halves (144B row stride: 16B-aligned,
    // non-pow2 bank spread)
    __shared__ _Float16 pbuf[4][16][72];

    const int t    = threadIdx.x;
    const int w    = t >> 6;
    const int lane = t & 63;
    const int lo   = lane & 15;
    const int quad = lane >> 4;
    const int b  = blockIdx.x >> 5;
    const int qt = blockIdx.x & 31;

    const _Float16* Qb = Q  + ((long)b * SEQ + qt * 64 + w * 16) * HS;
    const _Float16* Kb = K  + (long)b * SEQ * HS;
    const _Float16* Vb = Vt + (long)b * HS * SEQ;

    f16x8 qf0 = *(const f16x8*)(Qb + lo * HS + quad * 8);
    f16x8 qf1 = *(const f16x8*)(Qb + lo * HS + 32 + quad * 8);

    f32x4 o[4];
    float m_i[4], l_i[4];
#pragma unroll
    for (int r = 0; r < 4; ++r) {
        m_i[r] = -1e30f; l_i[r] = 0.f;
        o[0][r] = 0.f; o[1][r] = 0.f; o[2][r] = 0.f; o[3][r] = 0.f;
    }

    for (int kt = 0; kt < SEQ / 64; ++kt) {
        const _Float16* Kt  = Kb + (long)kt * 64 * HS;
        const _Float16* Vtt = Vb + kt * 64;

        // K fragments: B[n=lo][k] = K[key=nt*16+lo][k], 16B contiguous
        f16x8 kf[4][2];
#pragma unroll
        for (int nt = 0; nt < 4; ++nt) {
#pragma unroll
            for (int ks = 0; ks < 2; ++ks)
                kf[nt][ks] = *(const f16x8*)(Kt + (nt * 16 + lo) * HS + ks * 32 + quad * 8);
        }
        // first half of V fragments in flight early
        f16x8 vf0[4];
#pragma unroll
        for (int nt = 0; nt < 4; ++nt)
            vf0[nt] = *(const f16x8*)(Vtt + (long)(nt * 16 + lo) * SEQ + quad * 8);

        f32x4 s[4];
#pragma unroll
        for (int nt = 0; nt < 4; ++nt) { s[nt][0]=0.f; s[nt][1]=0.f; s[nt][2]=0.f; s[nt][3]=0.f; }
#pragma unroll
        for (int nt = 0; nt < 4; ++nt) {
            s[nt] = __builtin_amdgcn_mfma_f32_16x16x32_f16(qf0, kf[nt][0], s[nt], 0, 0, 0);
            s[nt] = __builtin_amdgcn_mfma_f32_16x16x32_f16(qf1, kf[nt][1], s[nt], 0, 0, 0);
        }

        // second half of V fragments (latency hidden by softmax)
        f16x8 vf1[4];
#pragma unroll
        for (int nt = 0; nt < 4; ++nt)
            vf1[nt] = *(const f16x8*)(Vtt + (long)(nt * 16 + lo) * SEQ + 32 + quad * 8);

        // online softmax, base-2 domain (scale folded into Q at proj time)
        float alpha[4];
#pragma unroll
        for (int r = 0; r < 4; ++r) {
            float mx = fmaxf(fmaxf(s[0][r], s[1][r]), fmaxf(s[2][r], s[3][r]));
            mx = fmaxf(mx, __shfl_xor(mx, 1));
            mx = fmaxf(mx, __shfl_xor(mx, 2));
            mx = fmaxf(mx, __shfl_xor(mx, 4));
            mx = fmaxf(mx, __shfl_xor(mx, 8));
            float mn = fmaxf(m_i[r], mx);
            alpha[r] = exp2f(m_i[r] - mn);
            m_i[r] = mn;
            float sum = 0.f;
#pragma unroll
            for (int nt = 0; nt < 4; ++nt) {
                float p = exp2f(s[nt][r] - mn);
                s[nt][r] = p;
                sum += p;
            }
            sum += __shfl_xor(sum, 1);
            sum += __shfl_xor(sum, 2);
            sum += __shfl_xor(sum, 4);
            sum += __shfl_xor(sum, 8);
            l_i[r] = l_i[r] * alpha[r] + sum;
        }

        // P: C-layout (row=quad*4+r, col=nt*16+lo) -> LDS -> A-layout
#pragma unroll
        for (int nt = 0; nt < 4; ++nt)
#pragma unroll
            for (int r = 0; r < 4; ++r)
                pbuf[w][quad * 4 + r][nt * 16 + lo] = (_Float16)s[nt][r];

        __syncthreads();   // fence LDS write -> cross-lane read

        f16x8 pf0 = *(const f16x8*)&pbuf[w][lo][quad * 8];
        f16x8 pf1 = *(const f16x8*)&pbuf[w][lo][32 + quad * 8];

#pragma unroll
        for (int nt = 0; nt < 4; ++nt) {
            o[nt][0] *= alpha[0]; o[nt][1] *= alpha[1];
            o[nt][2] *= alpha[2]; o[nt][3] *= alpha[3];
        }
#pragma unroll
        for (int nt = 0; nt < 4; ++nt) {
            o[nt] = __builtin_amdgcn_mfma_f32_16x16x32_f16(pf0, vf0[nt], o[nt], 0, 0, 0);
            o[nt] = __builtin_amdgcn_mfma_f32_16x16x32_f16(pf1, vf1[nt], o[nt], 0, 0, 0);
        }
    }

    float* ob = out + ((long)b * SEQ + qt * 64 + w * 16) * HS;
    float inv[4];
#pragma unroll
    for (int r = 0; r < 4; ++r) inv[r] = 1.f / l_i[r];
#pragma unroll
    for (int nt = 0; nt < 4; ++nt)
#pragma unroll
        for (int r = 0; r < 4; ++r)
            ob[(quad * 4 + r) * HS + nt * 16 + lo] = o[nt][r] * inv[r];
}

extern "C" void kernel_launch(void* const* d_in, const int* in_sizes, int n_in,
                              void* d_out, int out_size, void* d_ws, size_t ws_size,
                              hipStream_t stream)
{
    const float* x  = (const float*)d_in[0];
    const float* Wq = (const float*)d_in[1];
    const float* Wk = (const float*)d_in[2];
    const float* Wv = (const float*)d_in[3];
    float* out = (float*)d_out;

    const size_t elems = (size_t)BATCH * SEQ * HS;
    _Float16* Qh = (_Float16*)d_ws;
    _Float16* Kh = Qh + elems;
    _Float16* Vt = Kh + elems;   // 3 * 8.39 MB = 25.2 MB of d_ws

    proj_kernel<<<(BATCH * SEQ) / 64, 256, 0, stream>>>(x, Wq, Wk, Wv, Qh, Kh, Vt);
    attn_kernel<<<BATCH * (SEQ / 64), 256, 0, stream>>>(Qh, Kh, Vt, out);
}

// Round 3
// 316.634 us; speedup vs baseline: 3.9384x; 1.1286x over previous
//
#include <hip/hip_runtime.h>

// Head attention: B=32, S=2048, E=64, H=64, fp32 in/out, NO causal mask.
// R2: all-MFMA pipeline, barrier-free attention.
//  prep_w:  W (fp32) -> Wh (f16), Q-weights pre-scaled by 0.125*log2(e).
//  proj:    x @ W^T via mfma_f32_16x16x32_f16; Qh/Kh row-major f16,
//           V transposed through LDS -> Vt[b][h][s] f16 (coalesced stores).
//  attn:    per wave: 16 q-rows; per 64-key tile: 8 QK MFMAs -> raw f32
//           scores to per-wave LDS (C-layout) -> read back as PV A-frag
//           (row=lo) -> in-lane softmax (2 shfl_xor only) -> 8 PV MFMAs.
//           NO __syncthreads: per-wave LDS, intra-wave lgkmcnt ordering.

#define BATCH 32
#define SEQ   2048
#define HS    64
#define SPAD  68
#define QSCALE 0.18033688011112042f   // 0.125 * log2(e)

typedef _Float16 f16x8 __attribute__((ext_vector_type(8)));
typedef float    f32x4 __attribute__((ext_vector_type(4)));

__global__ __launch_bounds__(256) void prep_w(
    const float* __restrict__ Wq, const float* __restrict__ Wk,
    const float* __restrict__ Wv, _Float16* __restrict__ Wh)
{
    int i = blockIdx.x * 256 + threadIdx.x;   // 0..12287
    const float* src = (i < 4096) ? Wq : ((i < 8192) ? Wk : Wv);
    float scale = (i < 4096) ? QSCALE : 1.0f;
    Wh[i] = (_Float16)(src[i & 4095] * scale);
}

__global__ __launch_bounds__(256) void proj_kernel(
    const float* __restrict__ x, const _Float16* __restrict__ Wh,
    _Float16* __restrict__ Qh, _Float16* __restrict__ Kh,
    _Float16* __restrict__ Vt)
{
    __shared__ _Float16 vt[64][72];   // [h][s_local], stride 144B

    const int t    = threadIdx.x;
    const int w    = t >> 6;
    const int lane = t & 63;
    const int lo   = lane & 15;
    const int quad = lane >> 4;
    const long row0 = (long)blockIdx.x * 64;
    const int  b  = (int)(row0 / SEQ);
    const int  s0 = (int)(row0 % SEQ);
    const long rw = row0 + w * 16;    // this wave's first q-row

    // A fragments: x rows (fp32 -> f16)
    const float* xp = x + (rw + lo) * HS + quad * 8;
    float4 x0 = *(const float4*)xp;
    float4 x1 = *(const float4*)(xp + 4);
    float4 x2 = *(const float4*)(xp + 32);
    float4 x3 = *(const float4*)(xp + 36);
    f16x8 a0, a1;
    a0[0]=(_Float16)x0.x; a0[1]=(_Float16)x0.y; a0[2]=(_Float16)x0.z; a0[3]=(_Float16)x0.w;
    a0[4]=(_Float16)x1.x; a0[5]=(_Float16)x1.y; a0[6]=(_Float16)x1.z; a0[7]=(_Float16)x1.w;
    a1[0]=(_Float16)x2.x; a1[1]=(_Float16)x2.y; a1[2]=(_Float16)x2.z; a1[3]=(_Float16)x2.w;
    a1[4]=(_Float16)x3.x; a1[5]=(_Float16)x3.y; a1[6]=(_Float16)x3.z; a1[7]=(_Float16)x3.w;

#pragma unroll
    for (int m = 0; m < 3; ++m) {
        const _Float16* Wm = Wh + m * 4096 + lo * HS + quad * 8;
        f32x4 acc[4];
#pragma unroll
        for (int nt = 0; nt < 4; ++nt) { acc[nt][0]=0.f; acc[nt][1]=0.f; acc[nt][2]=0.f; acc[nt][3]=0.f; }
#pragma unroll
        for (int nt = 0; nt < 4; ++nt) {
            f16x8 b0 = *(const f16x8*)(Wm + nt * 16 * HS);
            f16x8 b1 = *(const f16x8*)(Wm + nt * 16 * HS + 32);
            acc[nt] = __builtin_amdgcn_mfma_f32_16x16x32_f16(a0, b0, acc[nt], 0, 0, 0);
            acc[nt] = __builtin_amdgcn_mfma_f32_16x16x32_f16(a1, b1, acc[nt], 0, 0, 0);
        }
        if (m < 2) {
            _Float16* dst = (m == 0) ? Qh : Kh;
#pragma unroll
            for (int nt = 0; nt < 4; ++nt)
#pragma unroll
                for (int r = 0; r < 4; ++r)
                    dst[(rw + quad * 4 + r) * HS + nt * 16 + lo] = (_Float16)acc[nt][r];
        } else {
#pragma unroll
            for (int nt = 0; nt < 4; ++nt)
#pragma unroll
                for (int r = 0; r < 4; ++r)
                    vt[nt * 16 + lo][w * 16 + quad * 4 + r] = (_Float16)acc[nt][r];
        }
    }

    __syncthreads();   // V transpose tile complete (once per block)

    const int h = t >> 2, seg = t & 3;
    f16x8 v0 = *(const f16x8*)&vt[h][seg * 16];
    f16x8 v1 = *(const f16x8*)&vt[h][seg * 16 + 8];
    _Float16* vd = Vt + ((long)b * HS + h) * SEQ + s0 + seg * 16;
    *(f16x8*)vd       = v0;
    *(f16x8*)(vd + 8) = v1;
}

__global__ __launch_bounds__(256, 4) void attn_kernel(
    const _Float16* __restrict__ Q, const _Float16* __restrict__ K,
    const _Float16* __restrict__ Vt, float* __restrict__ out)
{
    // per-wave raw-score scratch, f32, row stride 68 (16B-aligned, non-pow2)
    __shared__ float sbuf[4][16][SPAD];

    const int t    = threadIdx.x;
    const int w    = t >> 6;
    const int lane = t & 63;
    const int lo   = lane & 15;
    const int quad = lane >> 4;
    const int b  = blockIdx.x >> 5;
    const int qt = blockIdx.x & 31;

    const _Float16* Qb = Q  + ((long)b * SEQ + qt * 64 + w * 16) * HS;
    const _Float16* kp = K  + (long)b * SEQ * HS + lo * HS + quad * 8;  // lane base
    const _Float16* vp = Vt + (long)b * HS * SEQ + lo * SEQ + quad * 8; // lane base

    f16x8 qf0 = *(const f16x8*)(Qb + lo * HS + quad * 8);
    f16x8 qf1 = *(const f16x8*)(Qb + lo * HS + 32 + quad * 8);

    f32x4 o[4];
    float m_i = -1e30f, l_i = 0.f;
#pragma unroll
    for (int nt = 0; nt < 4; ++nt) { o[nt][0]=0.f; o[nt][1]=0.f; o[nt][2]=0.f; o[nt][3]=0.f; }

    for (int kt = 0; kt < SEQ / 64; ++kt) {
        // K fragments: B[n=nt*16+lo][k=ks*32+quad*8+j]
        f16x8 kf[4][2];
#pragma unroll
        for (int nt = 0; nt < 4; ++nt) {
            kf[nt][0] = *(const f16x8*)(kp + nt * 16 * HS);
            kf[nt][1] = *(const f16x8*)(kp + nt * 16 * HS + 32);
        }

        f32x4 s[4];
#pragma unroll
        for (int nt = 0; nt < 4; ++nt) { s[nt][0]=0.f; s[nt][1]=0.f; s[nt][2]=0.f; s[nt][3]=0.f; }
#pragma unroll
        for (int nt = 0; nt < 4; ++nt) {
            s[nt] = __builtin_amdgcn_mfma_f32_16x16x32_f16(qf0, kf[nt][0], s[nt], 0, 0, 0);
            s[nt] = __builtin_amdgcn_mfma_f32_16x16x32_f16(qf1, kf[nt][1], s[nt], 0, 0, 0);
        }

        // V fragments in flight during softmax
        f16x8 vf0[4], vf1[4];
#pragma unroll
        for (int nt = 0; nt < 4; ++nt) {
            vf0[nt] = *(const f16x8*)(vp + (long)nt * 16 * SEQ);
            vf1[nt] = *(const f16x8*)(vp + (long)nt * 16 * SEQ + 32);
        }

        // raw scores (base-2 domain) C-layout -> per-wave LDS
#pragma unroll
        for (int nt = 0; nt < 4; ++nt)
#pragma unroll
            for (int r = 0; r < 4; ++r)
                sbuf[w][quad * 4 + r][nt * 16 + lo] = s[nt][r];

        // read back as PV A-fragment rows (lgkmcnt dependence fences this)
        float4 c0 = *(const float4*)&sbuf[w][lo][quad * 8];
        float4 c1 = *(const float4*)&sbuf[w][lo][quad * 8 + 4];
        float4 c2 = *(const float4*)&sbuf[w][lo][32 + quad * 8];
        float4 c3 = *(const float4*)&sbuf[w][lo][32 + quad * 8 + 4];

        float mx = fmaxf(fmaxf(fmaxf(c0.x, c0.y), fmaxf(c0.z, c0.w)),
                   fmaxf(fmaxf(fmaxf(c1.x, c1.y), fmaxf(c1.z, c1.w)),
                   fmaxf(fmaxf(fmaxf(c2.x, c2.y), fmaxf(c2.z, c2.w)),
                         fmaxf(fmaxf(c3.x, c3.y), fmaxf(c3.z, c3.w)))));
        mx = fmaxf(mx, __shfl_xor(mx, 16));
        mx = fmaxf(mx, __shfl_xor(mx, 32));

        float mn    = fmaxf(m_i, mx);
        float alpha = exp2f(m_i - mn);
        m_i = mn;

        float e0 = exp2f(c0.x - mn), e1 = exp2f(c0.y - mn);
        float e2 = exp2f(c0.z - mn), e3 = exp2f(c0.w - mn);
        float e4 = exp2f(c1.x - mn), e5 = exp2f(c1.y - mn);
        float e6 = exp2f(c1.z - mn), e7 = exp2f(c1.w - mn);
        float f0 = exp2f(c2.x - mn), f1 = exp2f(c2.y - mn);
        float f2 = exp2f(c2.z - mn), f3 = exp2f(c2.w - mn);
        float f4 = exp2f(c3.x - mn), f5 = exp2f(c3.y - mn);
        float f6 = exp2f(c3.z - mn), f7 = exp2f(c3.w - mn);

        float sum = ((e0 + e1) + (e2 + e3)) + ((e4 + e5) + (e6 + e7)) +
                    ((f0 + f1) + (f2 + f3)) + ((f4 + f5) + (f6 + f7));
        sum += __shfl_xor(sum, 16);
        sum += __shfl_xor(sum, 32);
        l_i = l_i * alpha + sum;

        f16x8 pf0, pf1;
        pf0[0]=(_Float16)e0; pf0[1]=(_Float16)e1; pf0[2]=(_Float16)e2; pf0[3]=(_Float16)e3;
        pf0[4]=(_Float16)e4; pf0[5]=(_Float16)e5; pf0[6]=(_Float16)e6; pf0[7]=(_Float16)e7;
        pf1[0]=(_Float16)f0; pf1[1]=(_Float16)f1; pf1[2]=(_Float16)f2; pf1[3]=(_Float16)f3;
        pf1[4]=(_Float16)f4; pf1[5]=(_Float16)f5; pf1[6]=(_Float16)f6; pf1[7]=(_Float16)f7;

        // alpha for this lane's O rows (C-layout rows = quad*4+r)
        float ar0 = __shfl(alpha, quad * 4 + 0);
        float ar1 = __shfl(alpha, quad * 4 + 1);
        float ar2 = __shfl(alpha, quad * 4 + 2);
        float ar3 = __shfl(alpha, quad * 4 + 3);
#pragma unroll
        for (int nt = 0; nt < 4; ++nt) {
            o[nt][0] *= ar0; o[nt][1] *= ar1; o[nt][2] *= ar2; o[nt][3] *= ar3;
        }
#pragma unroll
        for (int nt = 0; nt < 4; ++nt) {
            o[nt] = __builtin_amdgcn_mfma_f32_16x16x32_f16(pf0, vf0[nt], o[nt], 0, 0, 0);
            o[nt] = __builtin_amdgcn_mfma_f32_16x16x32_f16(pf1, vf1[nt], o[nt], 0, 0, 0);
        }

        kp += 64 * HS;
        vp += 64;
    }

    float inv = 1.0f / l_i;
    float ir0 = __shfl(inv, quad * 4 + 0);
    float ir1 = __shfl(inv, quad * 4 + 1);
    float ir2 = __shfl(inv, quad * 4 + 2);
    float ir3 = __shfl(inv, quad * 4 + 3);

    float* ob = out + ((long)b * SEQ + qt * 64 + w * 16) * HS;
#pragma unroll
    for (int nt = 0; nt < 4; ++nt) {
        ob[(quad * 4 + 0) * HS + nt * 16 + lo] = o[nt][0] * ir0;
        ob[(quad * 4 + 1) * HS + nt * 16 + lo] = o[nt][1] * ir1;
        ob[(quad * 4 + 2) * HS + nt * 16 + lo] = o[nt][2] * ir2;
        ob[(quad * 4 + 3) * HS + nt * 16 + lo] = o[nt][3] * ir3;
    }
}

extern "C" void kernel_launch(void* const* d_in, const int* in_sizes, int n_in,
                              void* d_out, int out_size, void* d_ws, size_t ws_size,
                              hipStream_t stream)
{
    const float* x  = (const float*)d_in[0];
    const float* Wq = (const float*)d_in[1];
    const float* Wk = (const float*)d_in[2];
    const float* Wv = (const float*)d_in[3];
    float* out = (float*)d_out;

    const size_t elems = (size_t)BATCH * SEQ * HS;   // 4,194,304
    _Float16* Qh = (_Float16*)d_ws;
    _Float16* Kh = Qh + elems;
    _Float16* Vt = Kh + elems;
    _Float16* Wh = Vt + elems;    // 3*4096 f16

    prep_w<<<48, 256, 0, stream>>>(Wq, Wk, Wv, Wh);
    proj_kernel<<<(BATCH * SEQ) / 64, 256, 0, stream>>>(x, Wh, Qh, Kh, Vt);
    attn_kernel<<<BATCH * (SEQ / 64), 256, 0, stream>>>(Qh, Kh, Vt, out);
}